// Round 1
// baseline (1558.698 us; speedup 1.0000x reference)
//
#include <hip/hip_runtime.h>
#include <hip/hip_bf16.h>

#define D_IN 128
#define F 64   // H1 == H2 == D_OUT == 64

// ---------------- degree / dinv ----------------
__global__ void deg_count_kernel(const int* __restrict__ dst, float* __restrict__ deg, int E) {
    int t = blockIdx.x * blockDim.x + threadIdx.x;
    if (t < E) atomicAdd(&deg[dst[t]], 1.0f);
}

__global__ void dinv_kernel(float* __restrict__ deg, int n) {
    int t = blockIdx.x * blockDim.x + threadIdx.x;
    if (t < n) deg[t] = 1.0f / sqrtf(deg[t] + 1.0f);
}

// ---------------- fused GEMM + self-loop/bias init ----------------
// One wave (64 lanes) per row. Lane f computes h[row][f] = sum_k A[row][k]*W[k][f].
// W (K x 64, row-major) staged in LDS. A-row held in K/64 regs per lane, broadcast by shfl.
// Epilogue: h out (for the scatter) and outInit = dinv[row]^2 * h + b.
template<int K, bool RELU_IN>
__global__ __launch_bounds__(256) void gemm_rowwave_kernel(
        const float* __restrict__ A, const float* __restrict__ W,
        const float* __restrict__ b, const float* __restrict__ dinv,
        float* __restrict__ h, float* __restrict__ outInit, int n) {
    __shared__ float Wl[K * F];
    for (int i = threadIdx.x; i < K * F; i += blockDim.x) Wl[i] = W[i];
    __syncthreads();

    int wid  = (int)((blockIdx.x * (unsigned)blockDim.x + threadIdx.x) >> 6);
    int lane = threadIdx.x & 63;
    if (wid >= n) return;

    const float* arow = A + (size_t)wid * K;
    float xr[K / 64];
#pragma unroll
    for (int j = 0; j < K / 64; ++j) {
        float v = arow[j * 64 + lane];
        xr[j] = RELU_IN ? fmaxf(v, 0.0f) : v;
    }

    float acc = 0.0f;
#pragma unroll
    for (int j = 0; j < K / 64; ++j) {
#pragma unroll
        for (int k = 0; k < 64; ++k) {
            acc = fmaf(__shfl(xr[j], k), Wl[(j * 64 + k) * F + lane], acc);
        }
    }

    h[(size_t)wid * F + lane] = acc;
    float dv = dinv[wid];
    outInit[(size_t)wid * F + lane] = fmaf(dv * dv, acc, b[lane]);
}

// ---------------- edge scatter (atomic) ----------------
// One wave per edge; lane = feature. Gather h[src]*norm, atomicAdd into out[dst].
__global__ __launch_bounds__(256) void scatter_kernel(
        const int* __restrict__ src, const int* __restrict__ dst,
        const float* __restrict__ dinv, const float* __restrict__ h,
        float* __restrict__ out, int E) {
    long long t = (long long)blockIdx.x * blockDim.x + threadIdx.x;
    int e = (int)(t >> 6);
    if (e >= E) return;
    int f = (int)(t & 63);
    int s = src[e], d = dst[e];
    float norm = dinv[s] * dinv[d];
    atomicAdd(&out[(size_t)d * F + f], h[(size_t)s * F + f] * norm);
}

extern "C" void kernel_launch(void* const* d_in, const int* in_sizes, int n_in,
                              void* d_out, int out_size, void* d_ws, size_t ws_size,
                              hipStream_t stream) {
    const float* x   = (const float*)d_in[0];
    const float* W1  = (const float*)d_in[1];
    const float* b1  = (const float*)d_in[2];
    const float* W2  = (const float*)d_in[3];
    const float* b2  = (const float*)d_in[4];
    const float* W3  = (const float*)d_in[5];
    const float* b3  = (const float*)d_in[6];
    const int*   ei  = (const int*)d_in[7];

    const int n = in_sizes[0] / D_IN;       // 100000
    const int E = in_sizes[7] / 2;          // 1600000
    const int* src = ei;
    const int* dst = ei + E;

    // workspace layout (floats)
    float* ws   = (float*)d_ws;
    float* dinv = ws;                                   // n
    float* h    = ws + ((n + 255) & ~255);              // n*F
    float* out1 = h    + (size_t)n * F;                 // n*F
    float* out2 = out1 + (size_t)n * F;                 // n*F
    float* outF = (float*)d_out;

    // degree -> dinv
    hipMemsetAsync(dinv, 0, (size_t)n * sizeof(float), stream);
    deg_count_kernel<<<(E + 255) / 256, 256, 0, stream>>>(dst, dinv, E);
    dinv_kernel<<<(n + 255) / 256, 256, 0, stream>>>(dinv, n);

    const int gemm_grid = (n * 64 + 255) / 256;
    const long long sc_threads = (long long)E * 64;
    const int sc_grid = (int)((sc_threads + 255) / 256);

    // layer 1: x (K=128) -> out1
    gemm_rowwave_kernel<D_IN, false><<<gemm_grid, 256, 0, stream>>>(x, W1, b1, dinv, h, out1, n);
    scatter_kernel<<<sc_grid, 256, 0, stream>>>(src, dst, dinv, h, out1, E);

    // layer 2: relu(out1) (K=64) -> out2
    gemm_rowwave_kernel<F, true><<<gemm_grid, 256, 0, stream>>>(out1, W2, b2, dinv, h, out2, n);
    scatter_kernel<<<sc_grid, 256, 0, stream>>>(src, dst, dinv, h, out2, E);

    // layer 3: relu(out2) (K=64) -> d_out
    gemm_rowwave_kernel<F, true><<<gemm_grid, 256, 0, stream>>>(out2, W3, b3, dinv, h, outF, n);
    scatter_kernel<<<sc_grid, 256, 0, stream>>>(src, dst, dinv, h, outF, E);
}

// Round 2
// 1023.409 us; speedup vs baseline: 1.5230x; 1.5230x over previous
//
#include <hip/hip_runtime.h>
#include <hip/hip_bf16.h>

#define D_IN 128
#define F 64   // H1 == H2 == D_OUT == 64

// ============ preprocessing: degree histogram, dinv, scan, CSR fill ============

__global__ __launch_bounds__(256) void hist_kernel(const int* __restrict__ dst,
                                                   int* __restrict__ counts, int E) {
    int e = blockIdx.x * 256 + threadIdx.x;
    if (e < E) atomicAdd(&counts[dst[e]], 1);
}

__global__ __launch_bounds__(256) void dinv_kernel(const int* __restrict__ counts,
                                                   float* __restrict__ dinv, int n) {
    int i = blockIdx.x * 256 + threadIdx.x;
    if (i < n) dinv[i] = rsqrtf((float)counts[i] + 1.0f);
}

// block-level exclusive scan (block = 256), writes local-exclusive into offsets, block sum to bsum
__global__ __launch_bounds__(256) void scan1_kernel(const int* __restrict__ counts,
                                                    int* __restrict__ offsets,
                                                    int* __restrict__ bsum, int n) {
    __shared__ int tmp[256];
    int t = threadIdx.x;
    int i = blockIdx.x * 256 + t;
    int v = (i < n) ? counts[i] : 0;
    tmp[t] = v;
    __syncthreads();
    for (int off = 1; off < 256; off <<= 1) {
        int add = (t >= off) ? tmp[t - off] : 0;
        __syncthreads();
        if (t >= off) tmp[t] += add;
        __syncthreads();
    }
    if (i < n) offsets[i] = tmp[t] - v;           // exclusive
    if (t == 255) bsum[blockIdx.x] = tmp[t];      // inclusive block total
}

// single-block scan of block sums (nb <= 1024)
__global__ __launch_bounds__(1024) void scan2_kernel(int* __restrict__ bsum, int nb) {
    __shared__ int tmp[1024];
    int t = threadIdx.x;
    int v = (t < nb) ? bsum[t] : 0;
    tmp[t] = v;
    __syncthreads();
    for (int off = 1; off < 1024; off <<= 1) {
        int add = (t >= off) ? tmp[t - off] : 0;
        __syncthreads();
        if (t >= off) tmp[t] += add;
        __syncthreads();
    }
    if (t < nb) bsum[t] = tmp[t] - v;             // exclusive
}

__global__ __launch_bounds__(256) void scan3_kernel(int* __restrict__ offsets,
                                                    const int* __restrict__ bsum,
                                                    int* __restrict__ cursors, int n, int E) {
    int i = blockIdx.x * 256 + threadIdx.x;
    if (i < n) {
        int o = offsets[i] + bsum[i >> 8];
        offsets[i] = o;
        cursors[i] = o;
    }
    if (i == 0) offsets[n] = E;
}

__global__ __launch_bounds__(256) void fill_kernel(const int* __restrict__ src,
                                                   const int* __restrict__ dst,
                                                   int* __restrict__ cursors,
                                                   int* __restrict__ csr, int E) {
    int e = blockIdx.x * 256 + threadIdx.x;
    if (e < E) {
        int p = atomicAdd(&cursors[dst[e]], 1);
        csr[p] = src[e];
    }
}

// ============ GEMM: h2[row] = dinv[row] * (relu?(A[row]) @ W), W is K x 64 ============
// 64 rows/block, 256 threads, 4x4 outputs/thread, k-step 4 via float4, XOR-swizzled A tile.
template<int K, bool RELU_IN>
__global__ __launch_bounds__(256) void gemm_kernel(
        const float* __restrict__ A, const float* __restrict__ W,
        const float* __restrict__ dinv, float* __restrict__ h2, int n) {
    constexpr int F4 = K / 4;                 // float4s per A row (32 or 16)
    __shared__ float4 Al[64 * F4];            // swizzled: phys k4 = k4 ^ (rg & 7)
    __shared__ float  Wl[K * F];
    const int t = threadIdx.x;

    for (int i = t; i < K * F / 4; i += 256)
        ((float4*)Wl)[i] = ((const float4*)W)[i];

    const int row0 = blockIdx.x * 64;
    for (int i = t; i < 64 * F4; i += 256) {
        int r = i / F4, k4 = i % F4;
        int gr = row0 + r; if (gr >= n) gr = n - 1;   // clamp (dup read, stores guarded)
        float4 v = ((const float4*)(A + (size_t)gr * K))[k4];
        if (RELU_IN) {
            v.x = fmaxf(v.x, 0.f); v.y = fmaxf(v.y, 0.f);
            v.z = fmaxf(v.z, 0.f); v.w = fmaxf(v.w, 0.f);
        }
        Al[r * F4 + (k4 ^ ((r >> 2) & 7))] = v;
    }
    __syncthreads();

    const int rg = t >> 4;            // 0..15 (row group of 4)
    const int cg = t & 15;            // 0..15 (col group of 4)
    const int r0 = rg * 4, c0 = cg * 4;
    const int sw = rg & 7;            // swizzle key for rows 4rg..4rg+3

    float acc[4][4] = {};
    for (int k4 = 0; k4 < F4; ++k4) {
        float4 a[4];
#pragma unroll
        for (int i = 0; i < 4; ++i) a[i] = Al[(r0 + i) * F4 + (k4 ^ sw)];
#pragma unroll
        for (int j = 0; j < 4; ++j) {
            float4 w = *(const float4*)&Wl[(k4 * 4 + j) * F + c0];
#pragma unroll
            for (int i = 0; i < 4; ++i) {
                float av = (j == 0) ? a[i].x : (j == 1) ? a[i].y : (j == 2) ? a[i].z : a[i].w;
                acc[i][0] = fmaf(av, w.x, acc[i][0]);
                acc[i][1] = fmaf(av, w.y, acc[i][1]);
                acc[i][2] = fmaf(av, w.z, acc[i][2]);
                acc[i][3] = fmaf(av, w.w, acc[i][3]);
            }
        }
    }

#pragma unroll
    for (int i = 0; i < 4; ++i) {
        int gr = row0 + r0 + i;
        if (gr < n) {
            float dv = dinv[gr];
            float4 o = make_float4(acc[i][0] * dv, acc[i][1] * dv,
                                   acc[i][2] * dv, acc[i][3] * dv);
            *(float4*)&h2[(size_t)gr * F + c0] = o;
        }
    }
}

// ============ aggregation: out[i] = b + dinv[i] * (h2[i] + sum_{s in in(i)} h2[s]) ============
// one wave per node, lane = feature
__global__ __launch_bounds__(256) void agg_kernel(
        const int* __restrict__ offsets, const int* __restrict__ csr,
        const float* __restrict__ dinv, const float* __restrict__ h2,
        const float* __restrict__ b, float* __restrict__ out, int n) {
    int wid  = (int)((blockIdx.x * 256u + threadIdx.x) >> 6);
    int lane = threadIdx.x & 63;
    if (wid >= n) return;

    int beg = offsets[wid], end = offsets[wid + 1];
    float acc = h2[(size_t)wid * F + lane];   // self term

    int j = beg;
    for (; j + 4 <= end; j += 4) {
        int s0 = csr[j], s1 = csr[j + 1], s2 = csr[j + 2], s3 = csr[j + 3];
        float v0 = h2[(size_t)s0 * F + lane];
        float v1 = h2[(size_t)s1 * F + lane];
        float v2 = h2[(size_t)s2 * F + lane];
        float v3 = h2[(size_t)s3 * F + lane];
        acc += v0; acc += v1; acc += v2; acc += v3;
    }
    for (; j < end; ++j) acc += h2[(size_t)csr[j] * F + lane];

    out[(size_t)wid * F + lane] = fmaf(dinv[wid], acc, b[lane]);
}

// ============ launch ============
extern "C" void kernel_launch(void* const* d_in, const int* in_sizes, int n_in,
                              void* d_out, int out_size, void* d_ws, size_t ws_size,
                              hipStream_t stream) {
    const float* x   = (const float*)d_in[0];
    const float* W1  = (const float*)d_in[1];
    const float* b1  = (const float*)d_in[2];
    const float* W2  = (const float*)d_in[3];
    const float* b2  = (const float*)d_in[4];
    const float* W3  = (const float*)d_in[5];
    const float* b3  = (const float*)d_in[6];
    const int*   ei  = (const int*)d_in[7];

    const int n = in_sizes[0] / D_IN;       // 100000
    const int E = in_sizes[7] / 2;          // 1600000
    const int* src = ei;
    const int* dst = ei + E;

    // ---- workspace layout ----
    char* p = (char*)d_ws;
    auto alloc = [&](size_t bytes) { char* q = p; p += (bytes + 255) & ~(size_t)255; return q; };
    int*   counts  = (int*)  alloc((size_t)n * 4);
    int*   offsets = (int*)  alloc((size_t)(n + 1) * 4);
    int*   cursors = (int*)  alloc((size_t)n * 4);
    int*   bsum    = (int*)  alloc(1024 * 4);
    float* dinv    = (float*)alloc((size_t)n * 4);
    int*   csr     = (int*)  alloc((size_t)E * 4);
    float* h2      = (float*)alloc((size_t)n * F * 4);
    float* outA    = (float*)alloc((size_t)n * F * 4);
    float* outF    = (float*)d_out;

    const int nb      = (n + 255) / 256;        // scan blocks (391)
    const int eBlocks = (E + 255) / 256;
    const int gBlocks = (n + 63) / 64;
    const int aBlocks = (int)(((size_t)n * 64 + 255) / 256);

    // ---- degree + CSR build ----
    hipMemsetAsync(counts, 0, (size_t)n * 4, stream);
    hist_kernel <<<eBlocks, 256, 0, stream>>>(dst, counts, E);
    dinv_kernel <<<nb,      256, 0, stream>>>(counts, dinv, n);
    scan1_kernel<<<nb,      256, 0, stream>>>(counts, offsets, bsum, n);
    scan2_kernel<<<1,      1024, 0, stream>>>(bsum, nb);
    scan3_kernel<<<nb,      256, 0, stream>>>(offsets, bsum, cursors, n, E);
    fill_kernel <<<eBlocks, 256, 0, stream>>>(src, dst, cursors, csr, E);

    // ---- layer 1: x (K=128) ----
    gemm_kernel<D_IN, false><<<gBlocks, 256, 0, stream>>>(x, W1, dinv, h2, n);
    agg_kernel<<<aBlocks, 256, 0, stream>>>(offsets, csr, dinv, h2, b1, outA, n);

    // ---- layer 2: relu(outA) (K=64) ----
    gemm_kernel<F, true><<<gBlocks, 256, 0, stream>>>(outA, W2, dinv, h2, n);
    agg_kernel<<<aBlocks, 256, 0, stream>>>(offsets, csr, dinv, h2, b2, outA, n);

    // ---- layer 3: relu(outA) (K=64) ----
    gemm_kernel<F, true><<<gBlocks, 256, 0, stream>>>(outA, W3, dinv, h2, n);
    agg_kernel<<<aBlocks, 256, 0, stream>>>(offsets, csr, dinv, h2, b3, outF, n);
}

// Round 3
// 492.073 us; speedup vs baseline: 3.1676x; 2.0798x over previous
//
#include <hip/hip_runtime.h>
#include <hip/hip_bf16.h>

#define D_IN 128
#define F 64   // H1 == H2 == D_OUT == 64

// ============ preprocessing: degree histogram, dinv, scan, CSR fill ============

__global__ __launch_bounds__(256) void hist_kernel(const int* __restrict__ dst,
                                                   int* __restrict__ counts, int E) {
    int e = blockIdx.x * 256 + threadIdx.x;
    if (e < E) atomicAdd(&counts[dst[e]], 1);
}

__global__ __launch_bounds__(256) void dinv_kernel(const int* __restrict__ counts,
                                                   float* __restrict__ dinv, int n) {
    int i = blockIdx.x * 256 + threadIdx.x;
    if (i < n) dinv[i] = rsqrtf((float)counts[i] + 1.0f);
}

// block-level exclusive scan (block = 256), writes local-exclusive into offsets, block sum to bsum
__global__ __launch_bounds__(256) void scan1_kernel(const int* __restrict__ counts,
                                                    int* __restrict__ offsets,
                                                    int* __restrict__ bsum, int n) {
    __shared__ int tmp[256];
    int t = threadIdx.x;
    int i = blockIdx.x * 256 + t;
    int v = (i < n) ? counts[i] : 0;
    tmp[t] = v;
    __syncthreads();
    for (int off = 1; off < 256; off <<= 1) {
        int add = (t >= off) ? tmp[t - off] : 0;
        __syncthreads();
        if (t >= off) tmp[t] += add;
        __syncthreads();
    }
    if (i < n) offsets[i] = tmp[t] - v;           // exclusive
    if (t == 255) bsum[blockIdx.x] = tmp[t];      // inclusive block total
}

// single-block scan of block sums (nb <= 1024)
__global__ __launch_bounds__(1024) void scan2_kernel(int* __restrict__ bsum, int nb) {
    __shared__ int tmp[1024];
    int t = threadIdx.x;
    int v = (t < nb) ? bsum[t] : 0;
    tmp[t] = v;
    __syncthreads();
    for (int off = 1; off < 1024; off <<= 1) {
        int add = (t >= off) ? tmp[t - off] : 0;
        __syncthreads();
        if (t >= off) tmp[t] += add;
        __syncthreads();
    }
    if (t < nb) bsum[t] = tmp[t] - v;             // exclusive
}

__global__ __launch_bounds__(256) void scan3_kernel(int* __restrict__ offsets,
                                                    const int* __restrict__ bsum,
                                                    int* __restrict__ cursors, int n, int E) {
    int i = blockIdx.x * 256 + threadIdx.x;
    if (i < n) {
        int o = offsets[i] + bsum[i >> 8];
        offsets[i] = o;
        cursors[i] = o;
    }
    if (i == 0) offsets[n] = E;
}

__global__ __launch_bounds__(256) void fill_kernel(const int* __restrict__ src,
                                                   const int* __restrict__ dst,
                                                   int* __restrict__ cursors,
                                                   int* __restrict__ csr, int E) {
    int e = blockIdx.x * 256 + threadIdx.x;
    if (e < E) {
        int p = atomicAdd(&cursors[dst[e]], 1);
        csr[p] = src[e];
    }
}

// ============ GEMM: h2[row] = dinv[row] * (relu?(A[row]) @ W), W is K x 64 ============
// 64 rows/block, 256 threads, 4x4 outputs/thread, k-step 4 via float4, XOR-swizzled A tile.
// k4 loop unroll is CAPPED at 2: full unroll (R2) spilled to scratch (1.7 GB traffic, 570 us).
template<int K, bool RELU_IN>
__global__ __launch_bounds__(256) void gemm_kernel(
        const float* __restrict__ A, const float* __restrict__ W,
        const float* __restrict__ dinv, float* __restrict__ h2, int n) {
    constexpr int F4 = K / 4;                 // float4s per A row (32 or 16)
    __shared__ float4 Al[64 * F4];            // swizzled: phys k4 = k4 ^ (rg & 7)
    __shared__ float  Wl[K * F];
    const int t = threadIdx.x;

    for (int i = t; i < K * F / 4; i += 256)
        ((float4*)Wl)[i] = ((const float4*)W)[i];

    const int row0 = blockIdx.x * 64;
    for (int i = t; i < 64 * F4; i += 256) {
        int r = i / F4, k4 = i % F4;
        int gr = row0 + r; if (gr >= n) gr = n - 1;   // clamp (dup read, stores guarded)
        float4 v = ((const float4*)(A + (size_t)gr * K))[k4];
        if (RELU_IN) {
            v.x = fmaxf(v.x, 0.f); v.y = fmaxf(v.y, 0.f);
            v.z = fmaxf(v.z, 0.f); v.w = fmaxf(v.w, 0.f);
        }
        Al[r * F4 + (k4 ^ ((r >> 2) & 7))] = v;
    }
    __syncthreads();

    const int rg = t >> 4;            // 0..15 (row group of 4)
    const int cg = t & 15;            // 0..15 (col group of 4)
    const int r0 = rg * 4, c0 = cg * 4;
    const int sw = rg & 7;            // swizzle key for rows 4rg..4rg+3

    float acc[4][4] = {};
#pragma unroll 2
    for (int k4 = 0; k4 < F4; ++k4) {
        float4 a[4];
#pragma unroll
        for (int i = 0; i < 4; ++i) a[i] = Al[(r0 + i) * F4 + (k4 ^ sw)];
#pragma unroll
        for (int j = 0; j < 4; ++j) {
            float4 w = *(const float4*)&Wl[(k4 * 4 + j) * F + c0];
#pragma unroll
            for (int i = 0; i < 4; ++i) {
                float av = (j == 0) ? a[i].x : (j == 1) ? a[i].y : (j == 2) ? a[i].z : a[i].w;
                acc[i][0] = fmaf(av, w.x, acc[i][0]);
                acc[i][1] = fmaf(av, w.y, acc[i][1]);
                acc[i][2] = fmaf(av, w.z, acc[i][2]);
                acc[i][3] = fmaf(av, w.w, acc[i][3]);
            }
        }
    }

#pragma unroll
    for (int i = 0; i < 4; ++i) {
        int gr = row0 + r0 + i;
        if (gr < n) {
            float dv = dinv[gr];
            float4 o = make_float4(acc[i][0] * dv, acc[i][1] * dv,
                                   acc[i][2] * dv, acc[i][3] * dv);
            *(float4*)&h2[(size_t)gr * F + c0] = o;
        }
    }
}

// ============ aggregation: out[i] = b + dinv[i] * (h2[i] + sum_{s in in(i)} h2[s]) ============
// one wave per node, lane = feature
__global__ __launch_bounds__(256) void agg_kernel(
        const int* __restrict__ offsets, const int* __restrict__ csr,
        const float* __restrict__ dinv, const float* __restrict__ h2,
        const float* __restrict__ b, float* __restrict__ out, int n) {
    int wid  = (int)((blockIdx.x * 256u + threadIdx.x) >> 6);
    int lane = threadIdx.x & 63;
    if (wid >= n) return;

    int beg = offsets[wid], end = offsets[wid + 1];
    float acc = h2[(size_t)wid * F + lane];   // self term

    int j = beg;
    for (; j + 4 <= end; j += 4) {
        int s0 = csr[j], s1 = csr[j + 1], s2 = csr[j + 2], s3 = csr[j + 3];
        float v0 = h2[(size_t)s0 * F + lane];
        float v1 = h2[(size_t)s1 * F + lane];
        float v2 = h2[(size_t)s2 * F + lane];
        float v3 = h2[(size_t)s3 * F + lane];
        acc += v0; acc += v1; acc += v2; acc += v3;
    }
    for (; j < end; ++j) acc += h2[(size_t)csr[j] * F + lane];

    out[(size_t)wid * F + lane] = fmaf(dinv[wid], acc, b[lane]);
}

// ============ launch ============
extern "C" void kernel_launch(void* const* d_in, const int* in_sizes, int n_in,
                              void* d_out, int out_size, void* d_ws, size_t ws_size,
                              hipStream_t stream) {
    const float* x   = (const float*)d_in[0];
    const float* W1  = (const float*)d_in[1];
    const float* b1  = (const float*)d_in[2];
    const float* W2  = (const float*)d_in[3];
    const float* b2  = (const float*)d_in[4];
    const float* W3  = (const float*)d_in[5];
    const float* b3  = (const float*)d_in[6];
    const int*   ei  = (const int*)d_in[7];

    const int n = in_sizes[0] / D_IN;       // 100000
    const int E = in_sizes[7] / 2;          // 1600000
    const int* src = ei;
    const int* dst = ei + E;

    // ---- workspace layout ----
    char* p = (char*)d_ws;
    auto alloc = [&](size_t bytes) { char* q = p; p += (bytes + 255) & ~(size_t)255; return q; };
    int*   counts  = (int*)  alloc((size_t)n * 4);
    int*   offsets = (int*)  alloc((size_t)(n + 1) * 4);
    int*   cursors = (int*)  alloc((size_t)n * 4);
    int*   bsum    = (int*)  alloc(1024 * 4);
    float* dinv    = (float*)alloc((size_t)n * 4);
    int*   csr     = (int*)  alloc((size_t)E * 4);
    float* h2      = (float*)alloc((size_t)n * F * 4);
    float* outA    = (float*)alloc((size_t)n * F * 4);
    float* outF    = (float*)d_out;

    const int nb      = (n + 255) / 256;        // scan blocks (391)
    const int eBlocks = (E + 255) / 256;
    const int gBlocks = (n + 63) / 64;
    const int aBlocks = (int)(((size_t)n * 64 + 255) / 256);

    // ---- degree + CSR build ----
    hipMemsetAsync(counts, 0, (size_t)n * 4, stream);
    hist_kernel <<<eBlocks, 256, 0, stream>>>(dst, counts, E);
    dinv_kernel <<<nb,      256, 0, stream>>>(counts, dinv, n);
    scan1_kernel<<<nb,      256, 0, stream>>>(counts, offsets, bsum, n);
    scan2_kernel<<<1,      1024, 0, stream>>>(bsum, nb);
    scan3_kernel<<<nb,      256, 0, stream>>>(offsets, bsum, cursors, n, E);
    fill_kernel <<<eBlocks, 256, 0, stream>>>(src, dst, cursors, csr, E);

    // ---- layer 1: x (K=128) ----
    gemm_kernel<D_IN, false><<<gBlocks, 256, 0, stream>>>(x, W1, dinv, h2, n);
    agg_kernel<<<aBlocks, 256, 0, stream>>>(offsets, csr, dinv, h2, b1, outA, n);

    // ---- layer 2: relu(outA) (K=64) ----
    gemm_kernel<F, true><<<gBlocks, 256, 0, stream>>>(outA, W2, dinv, h2, n);
    agg_kernel<<<aBlocks, 256, 0, stream>>>(offsets, csr, dinv, h2, b2, outA, n);

    // ---- layer 3: relu(outA) (K=64) ----
    gemm_kernel<F, true><<<gBlocks, 256, 0, stream>>>(outA, W3, dinv, h2, n);
    agg_kernel<<<aBlocks, 256, 0, stream>>>(offsets, csr, dinv, h2, b3, outF, n);
}